// Round 1
// baseline (609.363 us; speedup 1.0000x reference)
//
#include <hip/hip_runtime.h>
#include <cstdint>
#include <cstddef>

// Problem dims (fixed by reference)
#define BATCH   4096
#define IN_DIM  2048
#define OUT_DIM 2048
#define KDIM    4096   // IN_DIM + OUT_DIM

typedef __bf16 bf16x8 __attribute__((ext_vector_type(8)));
typedef float  floatx4 __attribute__((ext_vector_type(4)));

__device__ __forceinline__ unsigned short f2bf(float f) {
  unsigned int u = __float_as_uint(f);
  u += 0x7FFFu + ((u >> 16) & 1u);   // round-to-nearest-even
  return (unsigned short)(u >> 16);
}

__device__ __forceinline__ void async16(const void* g, void* l) {
  __builtin_amdgcn_global_load_lds(
      (const __attribute__((address_space(1))) unsigned int*)g,
      (__attribute__((address_space(3))) unsigned int*)l, 16, 0, 0);
}

// ---------------------------------------------------------------------------
// Pack A = [X | H] row-major 4096 x 4096 bf16
// ---------------------------------------------------------------------------
__global__ __launch_bounds__(256) void pack_A_kernel(
    const float* __restrict__ X, const float* __restrict__ H,
    unsigned short* __restrict__ A) {
  int idx = blockIdx.x * 256 + threadIdx.x;   // 0 .. 4194303
  int e = idx << 2;                           // element index (groups of 4)
  int m = e >> 12;                            // /4096
  int k = e & 4095;
  const float* src = (k < IN_DIM) ? (X + (size_t)m * IN_DIM + k)
                                  : (H + (size_t)m * OUT_DIM + (k - IN_DIM));
  float4 v = *(const float4*)src;
  ushort4 o;
  o.x = f2bf(v.x); o.y = f2bf(v.y); o.z = f2bf(v.z); o.w = f2bf(v.w);
  *(ushort4*)(A + e) = o;
}

// ---------------------------------------------------------------------------
// Pack Bt: 8192(n) x 4096(k) bf16, n = gate*2048 + c, gates ordered f,i,o,g.
// Bt[n][k] = k<2048 ? W_x(g)[k][c] : W_h(g)[k-2048][c]   (a transpose)
// 32x32 LDS tile transpose so both global sides are coalesced.
// ---------------------------------------------------------------------------
__global__ __launch_bounds__(256) void pack_B_kernel(
    const float* __restrict__ Wxf, const float* __restrict__ Wxi,
    const float* __restrict__ Wxo, const float* __restrict__ Wxg,
    const float* __restrict__ Whf, const float* __restrict__ Whi,
    const float* __restrict__ Who, const float* __restrict__ Whg,
    unsigned short* __restrict__ Bt) {
  __shared__ float tile[32][33];   // +1 pad: no bank conflicts
  int bx = blockIdx.x;             // 0 .. 32767
  int nT = bx >> 7;                // 0..255
  int kT = bx & 127;               // 0..127
  int n0 = nT * 32, k0 = kT * 32;
  int g = n0 >> 11;                // gate (tiles never straddle: 2048%32==0)
  int c0 = n0 & 2047;
  const float* W;
  int kk0;
  if (k0 < IN_DIM) {
    kk0 = k0;
    W = (g == 0) ? Wxf : (g == 1) ? Wxi : (g == 2) ? Wxo : Wxg;
  } else {
    kk0 = k0 - IN_DIM;
    W = (g == 0) ? Whf : (g == 1) ? Whi : (g == 2) ? Who : Whg;
  }
  int t = threadIdx.x;
#pragma unroll
  for (int i = 0; i < 4; ++i) {
    int idx = i * 256 + t;
    int lk = idx >> 5, ln = idx & 31;
    tile[lk][ln] = W[(size_t)(kk0 + lk) * 2048 + c0 + ln];  // coalesced read
  }
  __syncthreads();
#pragma unroll
  for (int i = 0; i < 4; ++i) {
    int idx = i * 256 + t;
    int ln = idx >> 5, lk = idx & 31;
    Bt[(size_t)(n0 + ln) * KDIM + k0 + lk] = f2bf(tile[lk][ln]); // coalesced write
  }
}

// ---------------------------------------------------------------------------
// Fused LSTM GEMM: tile = 128(M) x 32 cols x 4 gates. 256 threads = 4 waves,
// wave (wm,wn) covers m: wm*64+[0,64), n: wn*16+[0,16) per gate.
// acc[gate][mt] -> all 4 gate pre-activations live in one workgroup, so the
// sigmoid/tanh/C_new/Y epilogue fuses here (no gates buffer, no 2nd pass).
// ---------------------------------------------------------------------------
__global__ __launch_bounds__(256) void lstm_gemm_fused(
    const unsigned short* __restrict__ A,    // 4096 x 4096 bf16
    const unsigned short* __restrict__ Bt,   // 8192 x 4096 bf16
    const float* __restrict__ Cin,           // 4096 x 2048
    const float* __restrict__ bF, const float* __restrict__ bI,
    const float* __restrict__ bO, const float* __restrict__ bG,
    float* __restrict__ outC, float* __restrict__ outY) {
  __shared__ unsigned short lA[128 * 32];    // 8 KB, no pad (global_load_lds)
  __shared__ unsigned short lB[128 * 32];    // 8 KB; rows = 4 gates x 32 n

  const int t = threadIdx.x;
  const int lane = t & 63;
  const int w = t >> 6;
  const int wm = w & 1, wn = w >> 1;
  const int mBase = blockIdx.y * 128;
  const int nBase = blockIdx.x * 32;         // within one gate's 2048 cols

  floatx4 acc[4][4];                         // [gate][mtile]
#pragma unroll
  for (int g = 0; g < 4; ++g)
#pragma unroll
    for (int mt = 0; mt < 4; ++mt) acc[g][mt] = (floatx4){0.f, 0.f, 0.f, 0.f};

  // ---- staging addresses (each thread moves 16 B per issue, 2 issues/matrix)
  const int rowA = t >> 2;                   // 0..63
  const int cb = (t & 3) * 16;               // byte offset within 64 B row run
  const char* aG0 = (const char*)(A + (size_t)(mBase + rowA) * KDIM) + cb;
  const char* aG1 = aG0 + (size_t)64 * KDIM * 2;
  const int r1 = 64 + rowA;
  const char* bG0 = (const char*)(Bt + (size_t)((rowA >> 5) * 2048 + nBase + (rowA & 31)) * KDIM) + cb;
  const char* bG1 = (const char*)(Bt + (size_t)((r1 >> 5) * 2048 + nBase + (r1 & 31)) * KDIM) + cb;
  char* lAdst = (char*)lA + t * 16;
  char* lBdst = (char*)lB + t * 16;

  const int fr = lane & 15;                  // fragment row (m or n)
  const int fk = lane >> 4;                  // which 8-wide k chunk

  for (int k0 = 0; k0 < KDIM; k0 += 32) {
    const int kb = k0 * 2;
    async16(aG0 + kb, lAdst);
    async16(aG1 + kb, lAdst + 4096);
    async16(bG0 + kb, lBdst);
    async16(bG1 + kb, lBdst + 4096);
    __syncthreads();                         // drains vmcnt, all waves staged

    const bf16x8* A8 = (const bf16x8*)lA;    // row = 4 chunks of 8 bf16
    const bf16x8* B8 = (const bf16x8*)lB;
    bf16x8 af[4], bf[4];
#pragma unroll
    for (int mt = 0; mt < 4; ++mt) af[mt] = A8[(wm * 64 + mt * 16 + fr) * 4 + fk];
#pragma unroll
    for (int g = 0; g < 4; ++g)   bf[g] = B8[(g * 32 + wn * 16 + fr) * 4 + fk];
#pragma unroll
    for (int g = 0; g < 4; ++g)
#pragma unroll
      for (int mt = 0; mt < 4; ++mt)
        acc[g][mt] = __builtin_amdgcn_mfma_f32_16x16x32_bf16(af[mt], bf[g], acc[g][mt], 0, 0, 0);
    __syncthreads();                         // protect LDS for next stage
  }

  // ---- fused LSTM epilogue. C/D layout: col=lane&15, row=(lane>>4)*4+reg
  const int col = nBase + wn * 16 + (lane & 15);        // 0..2047
  const int rbase = mBase + wm * 64 + (lane >> 4) * 4;
  const float bfv = bF[col], biv = bI[col], bov = bO[col], bgv = bG[col];
#pragma unroll
  for (int mt = 0; mt < 4; ++mt) {
#pragma unroll
    for (int r = 0; r < 4; ++r) {
      const int row = rbase + mt * 16 + r;
      const size_t off = (size_t)row * OUT_DIM + col;
      float pf = acc[0][mt][r] + bfv;
      float pi = acc[1][mt][r] + biv;
      float po = acc[2][mt][r] + bov;
      float pg = acc[3][mt][r] + bgv;
      float F = 1.f / (1.f + __expf(-pf));
      float I = 1.f / (1.f + __expf(-pi));
      float O = 1.f / (1.f + __expf(-po));
      float G = tanhf(pg);
      float c_new = G * I + F * Cin[off];
      outC[off] = c_new;
      outY[off] = O * tanhf(c_new);
    }
  }
}

// ---------------------------------------------------------------------------
extern "C" void kernel_launch(void* const* d_in, const int* in_sizes, int n_in,
                              void* d_out, int out_size, void* d_ws, size_t ws_size,
                              hipStream_t stream) {
  // setup_inputs order: X C H W_xf W_xg W_xi W_xo W_hf W_hg W_hi W_ho b_f b_g b_i b_o
  const float* X   = (const float*)d_in[0];
  const float* C   = (const float*)d_in[1];
  const float* H   = (const float*)d_in[2];
  const float* Wxf = (const float*)d_in[3];
  const float* Wxg = (const float*)d_in[4];
  const float* Wxi = (const float*)d_in[5];
  const float* Wxo = (const float*)d_in[6];
  const float* Whf = (const float*)d_in[7];
  const float* Whg = (const float*)d_in[8];
  const float* Whi = (const float*)d_in[9];
  const float* Who = (const float*)d_in[10];
  const float* bf_ = (const float*)d_in[11];
  const float* bg_ = (const float*)d_in[12];
  const float* bi_ = (const float*)d_in[13];
  const float* bo_ = (const float*)d_in[14];

  float* outC = (float*)d_out;
  float* outY = (float*)d_out + (size_t)BATCH * OUT_DIM;

  // workspace layout: A bf16 (32 MB) | Bt bf16 (64 MB)  => 96 MB needed
  unsigned short* A  = (unsigned short*)d_ws;
  unsigned short* Bt = A + (size_t)BATCH * KDIM;

  // 1) pack A = [X|H] -> bf16
  pack_A_kernel<<<(BATCH * KDIM / 4) / 256, 256, 0, stream>>>(X, H, A);
  // 2) pack Bt (transpose + gate concat + bf16)
  pack_B_kernel<<<256 * 128, 256, 0, stream>>>(Wxf, Wxi, Wxo, Wxg,
                                               Whf, Whi, Who, Whg, Bt);
  // 3) fused GEMM + LSTM epilogue
  dim3 grid(OUT_DIM / 32, BATCH / 128);      // (64, 32)
  lstm_gemm_fused<<<grid, 256, 0, stream>>>(A, Bt, C, bf_, bi_, bo_, bg_,
                                            outC, outY);
}

// Round 2
// 531.216 us; speedup vs baseline: 1.1471x; 1.1471x over previous
//
#include <hip/hip_runtime.h>
#include <cstdint>
#include <cstddef>

// Problem dims (fixed by reference)
#define BATCH   4096
#define IN_DIM  2048
#define OUT_DIM 2048
#define KDIM    4096   // IN_DIM + OUT_DIM

typedef __bf16 bf16x8 __attribute__((ext_vector_type(8)));
typedef float  floatx4 __attribute__((ext_vector_type(4)));

__device__ __forceinline__ unsigned short f2bf(float f) {
  unsigned int u = __float_as_uint(f);
  u += 0x7FFFu + ((u >> 16) & 1u);   // round-to-nearest-even
  return (unsigned short)(u >> 16);
}

__device__ __forceinline__ void async16(const void* g, void* l) {
  __builtin_amdgcn_global_load_lds(
      (const __attribute__((address_space(1))) unsigned int*)g,
      (__attribute__((address_space(3))) unsigned int*)l, 16, 0, 0);
}

// fast tanh via exp2-backed __expf; exact at saturation (exp overflow -> +-1)
__device__ __forceinline__ float tanh_fast(float x) {
  return 1.f - 2.f / (__expf(2.f * x) + 1.f);
}

// ---------------------------------------------------------------------------
// Pack A = [X | H] row-major 4096 x 4096 bf16
// ---------------------------------------------------------------------------
__global__ __launch_bounds__(256) void pack_A_kernel(
    const float* __restrict__ X, const float* __restrict__ H,
    unsigned short* __restrict__ A) {
  int idx = blockIdx.x * 256 + threadIdx.x;   // 0 .. 4194303
  int e = idx << 2;                           // element index (groups of 4)
  int m = e >> 12;                            // /4096
  int k = e & 4095;
  const float* src = (k < IN_DIM) ? (X + (size_t)m * IN_DIM + k)
                                  : (H + (size_t)m * OUT_DIM + (k - IN_DIM));
  float4 v = *(const float4*)src;
  ushort4 o;
  o.x = f2bf(v.x); o.y = f2bf(v.y); o.z = f2bf(v.z); o.w = f2bf(v.w);
  *(ushort4*)(A + e) = o;
}

// ---------------------------------------------------------------------------
// Pack Bt: 8192(n) x 4096(k) bf16, n = gate*2048 + c, gates ordered f,i,o,g.
// Bt[n][k] = k<2048 ? W_x(g)[k][c] : W_h(g)[k-2048][c]   (a transpose)
// 64(k) x 32(n) tiles: float4 global reads (128 B/8-lane row), uint4 writes
// (128 B per Bt row). LDS tile padded to 33 -> all phases <=2-way (free).
// ---------------------------------------------------------------------------
__global__ __launch_bounds__(256) void pack_B_kernel(
    const float* __restrict__ Wxf, const float* __restrict__ Wxi,
    const float* __restrict__ Wxo, const float* __restrict__ Wxg,
    const float* __restrict__ Whf, const float* __restrict__ Whi,
    const float* __restrict__ Who, const float* __restrict__ Whg,
    unsigned short* __restrict__ Bt) {
  __shared__ float tile[64][33];
  int bx = blockIdx.x;             // 0 .. 16383
  int kT = bx & 63;                // 0..63
  int nT = bx >> 6;                // 0..255
  int k0 = kT * 64, n0 = nT * 32;
  int g = n0 >> 11;                // gate; tiles never straddle (2048%32==0)
  int c0 = n0 & 2047;
  const float* W;
  int kk0;
  if (k0 < IN_DIM) {               // 2048 % 64 == 0: no straddle in k either
    kk0 = k0;
    W = (g == 0) ? Wxf : (g == 1) ? Wxi : (g == 2) ? Wxo : Wxg;
  } else {
    kk0 = k0 - IN_DIM;
    W = (g == 0) ? Whf : (g == 1) ? Whi : (g == 2) ? Who : Whg;
  }
  int t = threadIdx.x;
#pragma unroll
  for (int i = 0; i < 2; ++i) {
    int idx = i * 256 + t;
    int lk = idx >> 3, lc = (idx & 7) * 4;
    float4 v = *(const float4*)(W + (size_t)(kk0 + lk) * 2048 + c0 + lc);
    tile[lk][lc]     = v.x;
    tile[lk][lc + 1] = v.y;
    tile[lk][lc + 2] = v.z;
    tile[lk][lc + 3] = v.w;
  }
  __syncthreads();
  int ln = t >> 3, k8 = (t & 7) * 8;
  unsigned int p[4];
#pragma unroll
  for (int j = 0; j < 4; ++j) {
    unsigned int lo = f2bf(tile[k8 + 2 * j][ln]);
    unsigned int hi = f2bf(tile[k8 + 2 * j + 1][ln]);
    p[j] = lo | (hi << 16);
  }
  uint4 o = make_uint4(p[0], p[1], p[2], p[3]);
  *(uint4*)(Bt + (size_t)(n0 + ln) * KDIM + k0 + k8) = o;
}

// ---------------------------------------------------------------------------
// Fused LSTM GEMM: block tile = 256(M) x 32 cols x 4 gates (256x128 eff).
// 4 waves split M; wave covers 64 m x 128 eff n: 12 ds_read_b128 -> 32 MFMA
// per k-step (read:MFMA = 0.375 vs 0.5 before).
// LDS chunk swizzle c' = c ^ ((row>>1)&3): every 16-lane phase hits each
// 4-bank group exactly 2x (free). Swizzled chunk index is lane-constant.
// All 4 gates per workgroup -> LSTM epilogue fully fused.
// ---------------------------------------------------------------------------
__global__ __launch_bounds__(256, 2) void lstm_gemm_fused(
    const unsigned short* __restrict__ A,    // 4096 x 4096 bf16
    const unsigned short* __restrict__ Bt,   // 8192 x 4096 bf16
    const float* __restrict__ Cin,           // 4096 x 2048
    const float* __restrict__ bF, const float* __restrict__ bI,
    const float* __restrict__ bO, const float* __restrict__ bG,
    float* __restrict__ outC, float* __restrict__ outY) {
  __shared__ unsigned short lA[256 * 32];    // 16 KB
  __shared__ unsigned short lB[128 * 32];    // 8 KB; rows = 4 gates x 32 n

  const int t = threadIdx.x;
  const int lane = t & 63;
  const int w = t >> 6;                      // wave id: m-quarter
  const int mBase = blockIdx.y * 256;
  const int nBase = blockIdx.x * 32;         // within one gate's 2048 cols

  floatx4 acc[4][2][4];                      // [gate][nfrag][mtile]
#pragma unroll
  for (int g = 0; g < 4; ++g)
#pragma unroll
    for (int nf = 0; nf < 2; ++nf)
#pragma unroll
      for (int mt = 0; mt < 4; ++mt) acc[g][nf][mt] = (floatx4){0.f, 0.f, 0.f, 0.f};

  // ---- staging addresses. thread t stages LDS row (t>>2), chunk c'=(t&3);
  // swizzle: global chunk c = c' ^ ((row>>1)&3) = (t&3) ^ ((t>>3)&3).
  const int rowT = t >> 2;                   // 0..63
  const int cswz = (((t & 3) ^ ((t >> 3) & 3))) * 16;   // byte offset in row
  const char* aG = (const char*)(A + (size_t)(mBase + rowT) * KDIM) + cswz;
  const size_t aStep = (size_t)64 * KDIM * 2;           // 64 rows, bytes
  const int r1 = 64 + rowT;
  const char* bG0 = (const char*)(Bt + (size_t)((rowT >> 5) * 2048 + nBase + (rowT & 31)) * KDIM) + cswz;
  const char* bG1 = (const char*)(Bt + (size_t)((r1 >> 5) * 2048 + nBase + (r1 & 31)) * KDIM) + cswz;
  char* lAdst = (char*)lA + t * 16;
  char* lBdst = (char*)lB + t * 16;

  const int fr = lane & 15;                  // fragment row (m or n)
  const int fk = lane >> 4;                  // which 8-wide k chunk
  const int fkx = fk ^ ((fr >> 1) & 3);      // swizzled chunk (lane-constant)

  for (int k0 = 0; k0 < KDIM; k0 += 32) {
    const int kb = k0 * 2;
    async16(aG + kb,             lAdst);
    async16(aG + kb + aStep,     lAdst + 4096);
    async16(aG + kb + 2 * aStep, lAdst + 8192);
    async16(aG + kb + 3 * aStep, lAdst + 12288);
    async16(bG0 + kb,            lBdst);
    async16(bG1 + kb,            lBdst + 4096);
    __syncthreads();                         // drains vmcnt, all waves staged

    const bf16x8* A8 = (const bf16x8*)lA;
    const bf16x8* B8 = (const bf16x8*)lB;
    bf16x8 af[4], bfrag[8];
#pragma unroll
    for (int mt = 0; mt < 4; ++mt)
      af[mt] = A8[(w * 64 + mt * 16 + fr) * 4 + fkx];
#pragma unroll
    for (int g = 0; g < 4; ++g)
#pragma unroll
      for (int nf = 0; nf < 2; ++nf)
        bfrag[g * 2 + nf] = B8[(g * 32 + nf * 16 + fr) * 4 + fkx];
#pragma unroll
    for (int g = 0; g < 4; ++g)
#pragma unroll
      for (int nf = 0; nf < 2; ++nf)
#pragma unroll
        for (int mt = 0; mt < 4; ++mt)
          acc[g][nf][mt] = __builtin_amdgcn_mfma_f32_16x16x32_bf16(
              af[mt], bfrag[g * 2 + nf], acc[g][nf][mt], 0, 0, 0);
    __syncthreads();                         // protect LDS for next stage
  }

  // ---- fused LSTM epilogue. C/D layout: col=lane&15, row=(lane>>4)*4+reg
  const int col0 = nBase + (lane & 15);
  const int rb = mBase + w * 64 + (lane >> 4) * 4;
#pragma unroll
  for (int nf = 0; nf < 2; ++nf) {
    const int col = col0 + nf * 16;
    const float bfv = bF[col], biv = bI[col], bov = bO[col], bgv = bG[col];
#pragma unroll
    for (int mt = 0; mt < 4; ++mt) {
#pragma unroll
      for (int r = 0; r < 4; ++r) {
        const int row = rb + mt * 16 + r;
        const size_t off = (size_t)row * OUT_DIM + col;
        float pf = acc[0][nf][mt][r] + bfv;
        float pi = acc[1][nf][mt][r] + biv;
        float po = acc[2][nf][mt][r] + bov;
        float pg = acc[3][nf][mt][r] + bgv;
        float F = 1.f / (1.f + __expf(-pf));
        float I = 1.f / (1.f + __expf(-pi));
        float O = 1.f / (1.f + __expf(-po));
        float G = tanh_fast(pg);
        float c_new = G * I + F * Cin[off];
        outC[off] = c_new;
        outY[off] = O * tanh_fast(c_new);
      }
    }
  }
}

// ---------------------------------------------------------------------------
extern "C" void kernel_launch(void* const* d_in, const int* in_sizes, int n_in,
                              void* d_out, int out_size, void* d_ws, size_t ws_size,
                              hipStream_t stream) {
  // setup_inputs order: X C H W_xf W_xg W_xi W_xo W_hf W_hg W_hi W_ho b_f b_g b_i b_o
  const float* X   = (const float*)d_in[0];
  const float* C   = (const float*)d_in[1];
  const float* H   = (const float*)d_in[2];
  const float* Wxf = (const float*)d_in[3];
  const float* Wxg = (const float*)d_in[4];
  const float* Wxi = (const float*)d_in[5];
  const float* Wxo = (const float*)d_in[6];
  const float* Whf = (const float*)d_in[7];
  const float* Whg = (const float*)d_in[8];
  const float* Whi = (const float*)d_in[9];
  const float* Who = (const float*)d_in[10];
  const float* bf_ = (const float*)d_in[11];
  const float* bg_ = (const float*)d_in[12];
  const float* bi_ = (const float*)d_in[13];
  const float* bo_ = (const float*)d_in[14];

  float* outC = (float*)d_out;
  float* outY = (float*)d_out + (size_t)BATCH * OUT_DIM;

  // workspace layout: A bf16 (32 MB) | Bt bf16 (64 MB)  => 96 MB needed
  unsigned short* A  = (unsigned short*)d_ws;
  unsigned short* Bt = A + (size_t)BATCH * KDIM;

  // 1) pack A = [X|H] -> bf16
  pack_A_kernel<<<(BATCH * KDIM / 4) / 256, 256, 0, stream>>>(X, H, A);
  // 2) pack Bt (transpose + gate concat + bf16)
  pack_B_kernel<<<64 * 256, 256, 0, stream>>>(Wxf, Wxi, Wxo, Wxg,
                                              Whf, Whi, Who, Whg, Bt);
  // 3) fused GEMM + LSTM epilogue
  dim3 grid(OUT_DIM / 32, BATCH / 256);      // (64, 16)
  lstm_gemm_fused<<<grid, 256, 0, stream>>>(A, Bt, C, bf_, bi_, bo_, bg_,
                                            outC, outY);
}